// Round 2
// baseline (516.757 us; speedup 1.0000x reference)
//
#include <hip/hip_runtime.h>

typedef unsigned short u16;
typedef unsigned int   u32;
typedef __attribute__((ext_vector_type(8))) __bf16 bf16x8;
typedef __attribute__((ext_vector_type(8))) unsigned short u16x8;
typedef __attribute__((ext_vector_type(4))) float f32x4;

#define DEVINL static __device__ __forceinline__
#define MFMA16(a,b,c) __builtin_amdgcn_mfma_f32_16x16x32_bf16((a),(b),(c),0,0,0)

// Async global->LDS, 16B per lane. LDS dest must be (wave-uniform base + lane*16),
// which our linear chunk layout guarantees (chunk = i*256 + t).
#define GLOAD16(g, l) __builtin_amdgcn_global_load_lds( \
    (const __attribute__((address_space(1))) void*)(g), \
    (__attribute__((address_space(3))) void*)(l), 16, 0, 0)

constexpr float ATT_SCALE = 0.08838834764831845f;  // 128^-0.5

DEVINL u16 f2bf(float f) {
  union { float f; u32 u; } v; v.f = f;
  u32 r = v.u + 0x7fffu + ((v.u >> 16) & 1u);   // RNE, finite inputs only
  return (u16)(r >> 16);
}

// ---------------------------------------------------------------------------
// One-shot fp32 -> bf16 conversion of hs + the 4 weight matrices.
// grid = (4096, 5); each block converts 2048 elements (256 thr x 8).
// ---------------------------------------------------------------------------
struct CvtArgs {
  const float* src[5];
  u16*         dst[5];
  int          nblk[5];
};

__global__ __launch_bounds__(256) void cvt_bf16(CvtArgs a) {
  const int z = blockIdx.y;
  if (blockIdx.x >= a.nblk[z]) return;
  const size_t i = ((size_t)blockIdx.x * 256 + threadIdx.x) * 8;
  const float* s = a.src[z] + i;
  float4 x0 = *(const float4*)(s);
  float4 x1 = *(const float4*)(s + 4);
  u16x8 r;
  r[0]=f2bf(x0.x); r[1]=f2bf(x0.y); r[2]=f2bf(x0.z); r[3]=f2bf(x0.w);
  r[4]=f2bf(x1.x); r[5]=f2bf(x1.y); r[6]=f2bf(x1.z); r[7]=f2bf(x1.w);
  *(u16x8*)(a.dst[z] + i) = r;
}

// ---------------------------------------------------------------------------
// C[M,N] = A[M,K] * W[N,K]^T  (M=4096, N=2048, K=2048), all-bf16 inputs.
// m97 structure: 128x128 tile, BK=32, global_load_lds width-16, linear LDS.
// 4 waves, each computes 32 rows x 128 cols (2 m-frags x 8 n-frags).
// EPI: 0 = RoPE + store bf16 q/k as [b,h,s,d]
//      1 = store bf16 V transposed as [b,h,d,s] (via LDS transpose)
//      2 = plain fp32 store [M,N] (final output)
// ---------------------------------------------------------------------------
template<int EPI>
__global__ __launch_bounds__(256)
void gemm_nt(const u16* __restrict__ A, const u16* __restrict__ W,
             void* __restrict__ outp, const float* __restrict__ cosp,
             const float* __restrict__ sinp)
{
  __shared__ __attribute__((aligned(16))) u16 Alds[128*32];
  __shared__ __attribute__((aligned(16))) u16 Blds[128*32];
  __shared__ __attribute__((aligned(16))) u16 vtbuf[(EPI==1) ? 128*136 : 16];

  const int t    = threadIdx.x;
  const int bm   = blockIdx.x, bn = blockIdx.y;
  const int lane = t & 63, w = t >> 6;
  const int c    = lane & 15, qq = lane >> 4;

  f32x4 acc[2][8] = {};

  for (int kt = 0; kt < 64; ++kt) {
    __syncthreads();
    // Stage A and B tiles (8 KB each) via async global->LDS, 16B/lane.
    // chunk = i*256 + t; LDS byte off = chunk*16 == wave-uniform + lane*16.
    #pragma unroll
    for (int i = 0; i < 2; ++i) {
      const int chunk = i*256 + t;
      const int row   = chunk >> 2;        // 128 rows per tile
      const int seg   = chunk & 3;         // 4 x 16B per 64B row
      const u16* ga = A + (size_t)(bm*128 + row)*2048 + kt*32 + seg*8;
      GLOAD16(ga, &Alds[(size_t)chunk*8]);
      const u16* gb = W + (size_t)(bn*128 + row)*2048 + kt*32 + seg*8;
      GLOAD16(gb, &Blds[(size_t)chunk*8]);
    }
    __syncthreads();   // compiler drains vmcnt(0) before s_barrier

    bf16x8 a0 = *(const bf16x8*)&Alds[(w*32 +  0 + c)*32 + qq*8];
    bf16x8 a1 = *(const bf16x8*)&Alds[(w*32 + 16 + c)*32 + qq*8];
    #pragma unroll
    for (int nj = 0; nj < 8; ++nj) {
      bf16x8 bv = *(const bf16x8*)&Blds[(nj*16 + c)*32 + qq*8];
      acc[0][nj] = MFMA16(a0, bv, acc[0][nj]);
      acc[1][nj] = MFMA16(a1, bv, acc[1][nj]);
    }
  }

  if (EPI == 2) {
    float* out = (float*)outp;
    #pragma unroll
    for (int mi = 0; mi < 2; ++mi)
      #pragma unroll
      for (int nj = 0; nj < 8; ++nj)
        #pragma unroll
        for (int r = 0; r < 4; ++r) {
          int row = bm*128 + w*32 + mi*16 + qq*4 + r;
          int col = bn*128 + nj*16 + c;
          out[(size_t)row*2048 + col] = acc[mi][nj][r];
        }
  } else if (EPI == 0) {
    // RoPE in registers: n-frag nj holds d=nj*16+c (<64), nj+4 holds d+64.
    u16* qk = (u16*)outp;
    #pragma unroll
    for (int mi = 0; mi < 2; ++mi)
      #pragma unroll
      for (int r = 0; r < 4; ++r) {
        int m  = bm*128 + w*32 + mi*16 + qq*4 + r;
        int bb = m >> 11, s = m & 2047;
        const float* cs = cosp + s*128;
        const float* sn = sinp + s*128;
        u16* orow = qk + ((size_t)(bb*16 + bn)*2048 + s)*128;
        #pragma unroll
        for (int nj = 0; nj < 4; ++nj) {
          int d1 = nj*16 + c, d2 = d1 + 64;
          float v1 = acc[mi][nj][r], v2 = acc[mi][nj+4][r];
          orow[d1] = f2bf(v1*cs[d1] - v2*sn[d1]);
          orow[d2] = f2bf(v2*cs[d2] + v1*sn[d2]);
        }
      }
  } else {
    // V: transpose tile via LDS, store [b,h,d,s] coalesced.
    #pragma unroll
    for (int mi = 0; mi < 2; ++mi)
      #pragma unroll
      for (int nj = 0; nj < 8; ++nj)
        #pragma unroll
        for (int r = 0; r < 4; ++r)
          vtbuf[(nj*16 + c)*136 + w*32 + mi*16 + qq*4 + r] = f2bf(acc[mi][nj][r]);
    __syncthreads();
    int bb = bm >> 4;
    int s0 = (bm & 15) * 128;
    const int drow = t >> 1;
    const int half = (t & 1) * 64;
    u16* og = (u16*)outp + ((size_t)(bb*16 + bn)*128 + drow)*2048 + s0 + half;
    #pragma unroll
    for (int j = 0; j < 8; ++j)
      *(u16x8*)&og[j*8] = *(const u16x8*)&vtbuf[drow*136 + half + j*8];
  }
}

// ---------------------------------------------------------------------------
// Flash attention, causal. Per block: (q-tile 64 rows, head, batch); 4 waves,
// each wave owns 16 q-rows. KV tile = 64. K (row-major [64][128]) and
// V^T (row-major [128][64]) staged in LDS with XOR swizzle (G4: D=128 rows
// are 16-way bank conflicts unswizzled). Online softmax, 16-lane shuffles.
// ---------------------------------------------------------------------------
__global__ __launch_bounds__(256)
void attn_fwd(const u16* __restrict__ qw, const u16* __restrict__ kw,
              const u16* __restrict__ vw, u16* __restrict__ ow)
{
  __shared__ u16 Klds[64*128];
  __shared__ u16 Vlds[128*64];
  __shared__ u16 Plds[4][16*72];   // per-wave P tile, pad 72 -> conflict-free b128

  const int t = threadIdx.x, lane = t & 63, w = t >> 6;
  const int c = lane & 15, qq = lane >> 4;
  const int qt = blockIdx.x, h = blockIdx.y, b = blockIdx.z;

  const size_t bh = (size_t)b*16 + h;
  const u16* Qg = qw + bh*(2048*128);
  const u16* Kg = kw + bh*(2048*128);
  const u16* Vg = vw + bh*(128*2048);

  bf16x8 qf[4];
  {
    const int qrow = qt*64 + w*16 + c;
    #pragma unroll
    for (int ds = 0; ds < 4; ++ds)
      qf[ds] = *(const bf16x8*)(Qg + (size_t)qrow*128 + ds*32 + qq*8);
  }

  float m_r[4] = {-1e30f,-1e30f,-1e30f,-1e30f};
  float l_r[4] = {0.f,0.f,0.f,0.f};
  f32x4 oacc[8] = {};

  for (int kt = 0; kt <= qt; ++kt) {
    __syncthreads();
    { // K tile: contiguous 16KB, swizzled store
      const u16* src = Kg + (size_t)kt*(64*128);
      #pragma unroll
      for (int it = 0; it < 4; ++it) {
        u32 off = (u32)(it*256 + t) * 8;
        u32 sw  = off ^ (((off >> 7) & 7u) << 3);
        *(u16x8*)&Klds[sw] = *(const u16x8*)&src[off];
      }
    }
    { // V^T tile: 128 rows x 64, swizzled store
      const int vr   = t >> 1;
      const int voff = (t & 1) * 32;
      const u16* src = Vg + (size_t)vr*2048 + kt*64 + voff;
      #pragma unroll
      for (int j = 0; j < 4; ++j) {
        u32 off = (u32)(vr*64 + voff + j*8);
        u32 sw  = off ^ (((off >> 6) & 7u) << 3);
        *(u16x8*)&Vlds[sw] = *(const u16x8*)&src[j*8];
      }
    }
    __syncthreads();

    // S = Q K^T  (16 q x 64 k per wave)
    f32x4 sc[4] = {};
    #pragma unroll
    for (int ds = 0; ds < 4; ++ds) {
      #pragma unroll
      for (int nj = 0; nj < 4; ++nj) {
        u32 row = nj*16 + c;
        u32 p = (row*128 + ds*32 + qq*8) ^ ((row & 7u) << 3);
        bf16x8 kb = *(const bf16x8*)&Klds[p];
        sc[nj] = MFMA16(qf[ds], kb, sc[nj]);
      }
    }

    const int qg0 = qt*64 + w*16 + qq*4;
    const bool diag = (kt == qt);
    float escale[4];
    u16* pw = &Plds[w][0];
    #pragma unroll
    for (int r = 0; r < 4; ++r) {
      float mx = -1e30f;
      #pragma unroll
      for (int nj = 0; nj < 4; ++nj) {
        float s = sc[nj][r] * ATT_SCALE;
        if (diag && (kt*64 + nj*16 + c) > (qg0 + r)) s = -1e30f;
        sc[nj][r] = s;
        mx = fmaxf(mx, s);
      }
      mx = fmaxf(mx, __shfl_xor(mx, 1));
      mx = fmaxf(mx, __shfl_xor(mx, 2));
      mx = fmaxf(mx, __shfl_xor(mx, 4));
      mx = fmaxf(mx, __shfl_xor(mx, 8));
      float mnew = fmaxf(m_r[r], mx);
      escale[r] = __expf(m_r[r] - mnew);
      m_r[r] = mnew;
      float sum = 0.f;
      #pragma unroll
      for (int nj = 0; nj < 4; ++nj) {
        float pv = __expf(sc[nj][r] - mnew);
        sum += pv;
        pw[(qq*4 + r)*72 + nj*16 + c] = f2bf(pv);
      }
      sum += __shfl_xor(sum, 1);
      sum += __shfl_xor(sum, 2);
      sum += __shfl_xor(sum, 4);
      sum += __shfl_xor(sum, 8);
      l_r[r] = l_r[r]*escale[r] + sum;
    }

    #pragma unroll
    for (int nj8 = 0; nj8 < 8; ++nj8)
      #pragma unroll
      for (int r = 0; r < 4; ++r)
        oacc[nj8][r] *= escale[r];

    // O += P V   (A = P from per-wave LDS, B = V^T rows k-contiguous)
    #pragma unroll
    for (int ks = 0; ks < 2; ++ks) {
      bf16x8 pa = *(const bf16x8*)&pw[c*72 + ks*32 + qq*8];
      #pragma unroll
      for (int nj8 = 0; nj8 < 8; ++nj8) {
        u32 row = nj8*16 + c;
        u32 p = (row*64 + ks*32 + qq*8) ^ ((row & 7u) << 3);
        bf16x8 vb = *(const bf16x8*)&Vlds[p];
        oacc[nj8] = MFMA16(pa, vb, oacc[nj8]);
      }
    }
  }

  float inv[4];
  #pragma unroll
  for (int r = 0; r < 4; ++r) inv[r] = 1.0f / l_r[r];
  u16* og = ow + ((size_t)b*2048 + qt*64 + w*16)*2048 + h*128;
  #pragma unroll
  for (int nj8 = 0; nj8 < 8; ++nj8)
    #pragma unroll
    for (int r = 0; r < 4; ++r)
      og[(size_t)(qq*4 + r)*2048 + nj8*16 + c] = f2bf(oacc[nj8][r]*inv[r]);
}

extern "C" void kernel_launch(void* const* d_in, const int* in_sizes, int n_in,
                              void* d_out, int out_size, void* d_ws, size_t ws_size,
                              hipStream_t stream)
{
  const float* hs   = (const float*)d_in[0];
  const float* cosp = (const float*)d_in[1];
  const float* sinp = (const float*)d_in[2];
  const float* Wq   = (const float*)d_in[3];
  const float* Wk   = (const float*)d_in[4];
  const float* Wv   = (const float*)d_in[5];
  const float* Wo   = (const float*)d_in[6];

  // ws layout (u16 elements):
  //   q, k, v^T, attn_out : 4 x 8388608  (64 MB)
  //   hs_bf16             : 8388608      (16 MB)
  //   W{q,k,v,o}_bf16     : 4 x 4194304  (32 MB)   -> 112 MB total
  u16* q_ws  = (u16*)d_ws;
  u16* k_ws  = q_ws  + 8388608;
  u16* vt_ws = k_ws  + 8388608;
  u16* ao_ws = vt_ws + 8388608;
  u16* hs_b  = ao_ws + 8388608;
  u16* wq_b  = hs_b  + 8388608;
  u16* wk_b  = wq_b  + 4194304;
  u16* wv_b  = wk_b  + 4194304;
  u16* wo_b  = wv_b  + 4194304;

  CvtArgs ca;
  ca.src[0]=hs; ca.src[1]=Wq; ca.src[2]=Wk; ca.src[3]=Wv; ca.src[4]=Wo;
  ca.dst[0]=hs_b; ca.dst[1]=wq_b; ca.dst[2]=wk_b; ca.dst[3]=wv_b; ca.dst[4]=wo_b;
  ca.nblk[0]=4096; ca.nblk[1]=2048; ca.nblk[2]=2048; ca.nblk[3]=2048; ca.nblk[4]=2048;

  dim3 blk(256);
  cvt_bf16<<<dim3(4096, 5), blk, 0, stream>>>(ca);

  dim3 g(32, 16);
  gemm_nt<0><<<g, blk, 0, stream>>>(hs_b, wq_b, q_ws,  cosp, sinp);
  gemm_nt<0><<<g, blk, 0, stream>>>(hs_b, wk_b, k_ws,  cosp, sinp);
  gemm_nt<1><<<g, blk, 0, stream>>>(hs_b, wv_b, vt_ws, nullptr, nullptr);
  attn_fwd<<<dim3(32, 16, 2), blk, 0, stream>>>(q_ws, k_ws, vt_ws, ao_ws);
  gemm_nt<2><<<g, blk, 0, stream>>>(ao_ws, wo_b, d_out, nullptr, nullptr);
}

// Round 4
// 435.015 us; speedup vs baseline: 1.1879x; 1.1879x over previous
//
#include <hip/hip_runtime.h>

typedef unsigned short u16;
typedef unsigned int   u32;
typedef __attribute__((ext_vector_type(8))) __bf16 bf16x8;
typedef __attribute__((ext_vector_type(8))) unsigned short u16x8;
typedef __attribute__((ext_vector_type(4))) float f32x4;

#define DEVINL static __device__ __forceinline__
#define MFMA16(a,b,c) __builtin_amdgcn_mfma_f32_16x16x32_bf16((a),(b),(c),0,0,0)

// Async global->LDS, 16B per lane. LDS dest must be (wave-uniform base + lane*16).
#define GLOAD16(g, l) __builtin_amdgcn_global_load_lds( \
    (const __attribute__((address_space(1))) void*)(g), \
    (__attribute__((address_space(3))) void*)(l), 16, 0, 0)

constexpr float ATT_SCALE = 0.08838834764831845f;  // 128^-0.5

DEVINL u16 f2bf(float f) {
  union { float f; u32 u; } v; v.f = f;
  u32 r = v.u + 0x7fffu + ((v.u >> 16) & 1u);   // RNE, finite inputs only
  return (u16)(r >> 16);
}

// ---------------------------------------------------------------------------
// One-shot fp32 -> bf16 conversion of hs + the 4 weight matrices.
// ---------------------------------------------------------------------------
struct CvtArgs {
  const float* src[5];
  u16*         dst[5];
  int          nblk[5];
};

__global__ __launch_bounds__(256) void cvt_bf16(CvtArgs a) {
  const int z = blockIdx.y;
  if (blockIdx.x >= a.nblk[z]) return;
  const size_t i = ((size_t)blockIdx.x * 256 + threadIdx.x) * 8;
  const float* s = a.src[z] + i;
  float4 x0 = *(const float4*)(s);
  float4 x1 = *(const float4*)(s + 4);
  u16x8 r;
  r[0]=f2bf(x0.x); r[1]=f2bf(x0.y); r[2]=f2bf(x0.z); r[3]=f2bf(x0.w);
  r[4]=f2bf(x1.x); r[5]=f2bf(x1.y); r[6]=f2bf(x1.z); r[7]=f2bf(x1.w);
  *(u16x8*)(a.dst[z] + i) = r;
}

// ---------------------------------------------------------------------------
// C[M,N] = A[M,K] * W[N,K]^T  (M=4096, N=2048, K=2048), all-bf16 inputs.
// m97 structure: 128x128 tile, BK=32, global_load_lds width-16, linear LDS.
// (measured round 2: ~75-80 us each ≈ 880 TF — at this structure's ceiling)
// ---------------------------------------------------------------------------
template<int EPI>
__global__ __launch_bounds__(256)
void gemm_nt(const u16* __restrict__ A, const u16* __restrict__ W,
             void* __restrict__ outp, const float* __restrict__ cosp,
             const float* __restrict__ sinp)
{
  __shared__ __attribute__((aligned(16))) u16 Alds[128*32];
  __shared__ __attribute__((aligned(16))) u16 Blds[128*32];
  __shared__ __attribute__((aligned(16))) u16 vtbuf[(EPI==1) ? 128*136 : 16];

  const int t    = threadIdx.x;
  const int bm   = blockIdx.x, bn = blockIdx.y;
  const int lane = t & 63, w = t >> 6;
  const int c    = lane & 15, qq = lane >> 4;

  f32x4 acc[2][8] = {};

  for (int kt = 0; kt < 64; ++kt) {
    __syncthreads();
    #pragma unroll
    for (int i = 0; i < 2; ++i) {
      const int chunk = i*256 + t;
      const int row   = chunk >> 2;
      const int seg   = chunk & 3;
      const u16* ga = A + (size_t)(bm*128 + row)*2048 + kt*32 + seg*8;
      GLOAD16(ga, &Alds[(size_t)chunk*8]);
      const u16* gb = W + (size_t)(bn*128 + row)*2048 + kt*32 + seg*8;
      GLOAD16(gb, &Blds[(size_t)chunk*8]);
    }
    __syncthreads();

    bf16x8 a0 = *(const bf16x8*)&Alds[(w*32 +  0 + c)*32 + qq*8];
    bf16x8 a1 = *(const bf16x8*)&Alds[(w*32 + 16 + c)*32 + qq*8];
    #pragma unroll
    for (int nj = 0; nj < 8; ++nj) {
      bf16x8 bv = *(const bf16x8*)&Blds[(nj*16 + c)*32 + qq*8];
      acc[0][nj] = MFMA16(a0, bv, acc[0][nj]);
      acc[1][nj] = MFMA16(a1, bv, acc[1][nj]);
    }
  }

  if (EPI == 2) {
    float* out = (float*)outp;
    #pragma unroll
    for (int mi = 0; mi < 2; ++mi)
      #pragma unroll
      for (int nj = 0; nj < 8; ++nj)
        #pragma unroll
        for (int r = 0; r < 4; ++r) {
          int row = bm*128 + w*32 + mi*16 + qq*4 + r;
          int col = bn*128 + nj*16 + c;
          out[(size_t)row*2048 + col] = acc[mi][nj][r];
        }
  } else if (EPI == 0) {
    // RoPE in registers: n-frag nj holds d=nj*16+c (<64), nj+4 holds d+64.
    u16* qk = (u16*)outp;
    #pragma unroll
    for (int mi = 0; mi < 2; ++mi)
      #pragma unroll
      for (int r = 0; r < 4; ++r) {
        int m  = bm*128 + w*32 + mi*16 + qq*4 + r;
        int bb = m >> 11, s = m & 2047;
        const float* cs = cosp + s*128;
        const float* sn = sinp + s*128;
        u16* orow = qk + ((size_t)(bb*16 + bn)*2048 + s)*128;
        #pragma unroll
        for (int nj = 0; nj < 4; ++nj) {
          int d1 = nj*16 + c, d2 = d1 + 64;
          float v1 = acc[mi][nj][r], v2 = acc[mi][nj+4][r];
          orow[d1] = f2bf(v1*cs[d1] - v2*sn[d1]);
          orow[d2] = f2bf(v2*cs[d2] + v1*sn[d2]);
        }
      }
  } else {
    // V: transpose tile via LDS, store [b,h,d,s] coalesced.
    #pragma unroll
    for (int mi = 0; mi < 2; ++mi)
      #pragma unroll
      for (int nj = 0; nj < 8; ++nj)
        #pragma unroll
        for (int r = 0; r < 4; ++r)
          vtbuf[(nj*16 + c)*136 + w*32 + mi*16 + qq*4 + r] = f2bf(acc[mi][nj][r]);
    __syncthreads();
    int bb = bm >> 4;
    int s0 = (bm & 15) * 128;
    const int drow = t >> 1;
    const int half = (t & 1) * 64;
    u16* og = (u16*)outp + ((size_t)(bb*16 + bn)*128 + drow)*2048 + s0 + half;
    #pragma unroll
    for (int j = 0; j < 8; ++j)
      *(u16x8*)&og[j*8] = *(const u16x8*)&vtbuf[drow*136 + half + j*8];
  }
}

// ---------------------------------------------------------------------------
// Flash attention, causal, PAIRED q-tiles for load balance.
// Block (i,h,b), i in 0..15: owns q-tiles qlo=i and qhi=31-i. One shared KV
// loop kt=0..qhi; lo tile active while kt<=qlo -> uniform 33 tile-computes
// per block, 512 blocks = 2/CU.
// K/V double-buffered in LDS via global_load_lds with PRE-SWIZZLED per-lane
// global source (linear LDS dest, XOR-involution on 16B granules); next tile
// prefetch issued right after the single per-iter barrier (2-phase pipeline).
// 4 waves x 16 q-rows per tile; online softmax via 16-lane shuffles.
// ---------------------------------------------------------------------------
__global__ __launch_bounds__(256, 2)
void attn_fwd(const u16* __restrict__ qw, const u16* __restrict__ kw,
              const u16* __restrict__ vw, u16* __restrict__ ow)
{
  __shared__ __attribute__((aligned(16))) u16 Klds[2][64*128];
  __shared__ __attribute__((aligned(16))) u16 Vlds[2][128*64];
  __shared__ __attribute__((aligned(16))) u16 Plds[4][16*72];

  const int t = threadIdx.x, lane = t & 63, w = t >> 6;
  const int c = lane & 15, qq = lane >> 4;
  const int ip = blockIdx.x, h = blockIdx.y, b = blockIdx.z;
  const int qlo = ip, qhi = 31 - ip;

  const size_t bh = (size_t)b*16 + h;
  const u16* Qg = qw + bh*(2048*128);
  const u16* Kg = kw + bh*(2048*128);
  const u16* Vg = vw + bh*(128*2048);
  u16* pw = &Plds[w][0];

  // Q fragments for both tiles (rows: qt*64 + w*16 + c)
  bf16x8 qf_hi[4], qf_lo[4];
  {
    const u16* qh = Qg + (size_t)(qhi*64 + w*16 + c)*128;
    const u16* ql = Qg + (size_t)(qlo*64 + w*16 + c)*128;
    #pragma unroll
    for (int ds = 0; ds < 4; ++ds) {
      qf_hi[ds] = *(const bf16x8*)(qh + ds*32 + qq*8);
      qf_lo[ds] = *(const bf16x8*)(ql + ds*32 + qq*8);
    }
  }

  float m_hi[4] = {-1e30f,-1e30f,-1e30f,-1e30f};
  float l_hi[4] = {0.f,0.f,0.f,0.f};
  f32x4 o_hi[8] = {};
  float m_lo[4] = {-1e30f,-1e30f,-1e30f,-1e30f};
  float l_lo[4] = {0.f,0.f,0.f,0.f};
  f32x4 o_lo[8] = {};

  // Stage tile kt into buffer buf. Linear LDS dest (granule p = lane-linear),
  // global source at inverse-swizzled granule gl (XOR is an involution).
  // K granule map: phys = logical ^ ((logical>>4)&7)  (tile = 1024 granules)
  // V granule map: phys = logical ^ ((logical>>3)&7)  (V^T row = 8 granules)
#define STAGE(BUF, KT) do {                                                   \
    const u16* kbase = Kg + (size_t)(KT)*8192;                                \
    _Pragma("unroll")                                                         \
    for (int it = 0; it < 4; ++it) {                                          \
      const u32 p  = it*256 + t;                                              \
      const u32 gl = p ^ ((p >> 4) & 7u);                                     \
      GLOAD16(kbase + gl*8, &Klds[BUF][p*8]);                                 \
    }                                                                         \
    _Pragma("unroll")                                                         \
    for (int it = 0; it < 4; ++it) {                                          \
      const u32 p  = it*256 + t;                                              \
      const u32 gl = p ^ ((p >> 3) & 7u);                                     \
      GLOAD16(Vg + (size_t)(gl >> 3)*2048 + (KT)*64 + (gl & 7u)*8,            \
              &Vlds[BUF][p*8]);                                               \
    }                                                                         \
  } while (0)

  // Full tile step for one q-tile: QK^T -> online softmax -> P(LDS) -> PV.
#define PROCESS(QF, OACC, MR, LR, QBASE, DIAG, BUF) do {                      \
    f32x4 sc[4] = {};                                                         \
    __builtin_amdgcn_s_setprio(1);                                            \
    _Pragma("unroll")                                                         \
    for (int ds = 0; ds < 4; ++ds) {                                          \
      _Pragma("unroll")                                                       \
      for (int nj = 0; nj < 4; ++nj) {                                        \
        const u32 row = nj*16 + c;                                            \
        const u32 p = (row*128 + ds*32 + qq*8) ^ ((row & 7u) << 3);           \
        bf16x8 kb = *(const bf16x8*)&Klds[BUF][p];                            \
        sc[nj] = MFMA16(QF[ds], kb, sc[nj]);                                  \
      }                                                                       \
    }                                                                         \
    __builtin_amdgcn_s_setprio(0);                                            \
    const int qg0 = (QBASE) + w*16 + qq*4;                                    \
    float escale[4];                                                          \
    _Pragma("unroll")                                                         \
    for (int r = 0; r < 4; ++r) {                                             \
      float mx = -1e30f;                                                      \
      _Pragma("unroll")                                                       \
      for (int nj = 0; nj < 4; ++nj) {                                        \
        float s = sc[nj][r] * ATT_SCALE;                                      \
        if ((DIAG) && (kt*64 + nj*16 + c) > (qg0 + r)) s = -1e30f;            \
        sc[nj][r] = s;                                                        \
        mx = fmaxf(mx, s);                                                    \
      }                                                                       \
      mx = fmaxf(mx, __shfl_xor(mx, 1));                                      \
      mx = fmaxf(mx, __shfl_xor(mx, 2));                                      \
      mx = fmaxf(mx, __shfl_xor(mx, 4));                                      \
      mx = fmaxf(mx, __shfl_xor(mx, 8));                                      \
      float mnew = fmaxf(MR[r], mx);                                          \
      escale[r] = __expf(MR[r] - mnew);                                       \
      MR[r] = mnew;                                                           \
      float sum = 0.f;                                                        \
      _Pragma("unroll")                                                       \
      for (int nj = 0; nj < 4; ++nj) {                                        \
        float pv = __expf(sc[nj][r] - mnew);                                  \
        sum += pv;                                                            \
        pw[(qq*4 + r)*72 + nj*16 + c] = f2bf(pv);                             \
      }                                                                       \
      sum += __shfl_xor(sum, 1);                                              \
      sum += __shfl_xor(sum, 2);                                              \
      sum += __shfl_xor(sum, 4);                                              \
      sum += __shfl_xor(sum, 8);                                              \
      LR[r] = LR[r]*escale[r] + sum;                                          \
    }                                                                         \
    _Pragma("unroll")                                                         \
    for (int nj8 = 0; nj8 < 8; ++nj8)                                         \
      _Pragma("unroll")                                                       \
      for (int r = 0; r < 4; ++r)                                             \
        OACC[nj8][r] *= escale[r];                                            \
    __builtin_amdgcn_s_setprio(1);                                            \
    _Pragma("unroll")                                                         \
    for (int ks = 0; ks < 2; ++ks) {                                          \
      bf16x8 pa = *(const bf16x8*)&pw[c*72 + ks*32 + qq*8];                   \
      _Pragma("unroll")                                                       \
      for (int nj8 = 0; nj8 < 8; ++nj8) {                                     \
        const u32 row = nj8*16 + c;                                           \
        const u32 p = (row*64 + ks*32 + qq*8) ^ ((row & 7u) << 3);            \
        bf16x8 vb = *(const bf16x8*)&Vlds[BUF][p];                            \
        OACC[nj8] = MFMA16(pa, vb, OACC[nj8]);                                \
      }                                                                       \
    }                                                                         \
    __builtin_amdgcn_s_setprio(0);                                            \
  } while (0)

  STAGE(0, 0);
  for (int kt = 0; kt <= qhi; ++kt) {
    const int cur = kt & 1;
    __syncthreads();                     // drains vmcnt -> buf[cur] ready
    if (kt < qhi) STAGE(cur ^ 1, kt + 1);  // prefetch overlaps compute below
    PROCESS(qf_hi, o_hi, m_hi, l_hi, qhi*64, (kt == qhi), cur);
    if (kt <= qlo)
      PROCESS(qf_lo, o_lo, m_lo, l_lo, qlo*64, (kt == qlo), cur);
  }

#undef STAGE
#undef PROCESS

  // Epilogue: O /= l, store bf16 at [b, s, h*128]
  {
    float inv[4];
    #pragma unroll
    for (int r = 0; r < 4; ++r) inv[r] = 1.0f / l_hi[r];
    u16* og = ow + ((size_t)b*2048 + qhi*64 + w*16)*2048 + h*128;
    #pragma unroll
    for (int nj8 = 0; nj8 < 8; ++nj8)
      #pragma unroll
      for (int r = 0; r < 4; ++r)
        og[(size_t)(qq*4 + r)*2048 + nj8*16 + c] = f2bf(o_hi[nj8][r]*inv[r]);
  }
  {
    float inv[4];
    #pragma unroll
    for (int r = 0; r < 4; ++r) inv[r] = 1.0f / l_lo[r];
    u16* og = ow + ((size_t)b*2048 + qlo*64 + w*16)*2048 + h*128;
    #pragma unroll
    for (int nj8 = 0; nj8 < 8; ++nj8)
      #pragma unroll
      for (int r = 0; r < 4; ++r)
        og[(size_t)(qq*4 + r)*2048 + nj8*16 + c] = f2bf(o_lo[nj8][r]*inv[r]);
  }
}

extern "C" void kernel_launch(void* const* d_in, const int* in_sizes, int n_in,
                              void* d_out, int out_size, void* d_ws, size_t ws_size,
                              hipStream_t stream)
{
  const float* hs   = (const float*)d_in[0];
  const float* cosp = (const float*)d_in[1];
  const float* sinp = (const float*)d_in[2];
  const float* Wq   = (const float*)d_in[3];
  const float* Wk   = (const float*)d_in[4];
  const float* Wv   = (const float*)d_in[5];
  const float* Wo   = (const float*)d_in[6];

  u16* q_ws  = (u16*)d_ws;
  u16* k_ws  = q_ws  + 8388608;
  u16* vt_ws = k_ws  + 8388608;
  u16* ao_ws = vt_ws + 8388608;
  u16* hs_b  = ao_ws + 8388608;
  u16* wq_b  = hs_b  + 8388608;
  u16* wk_b  = wq_b  + 4194304;
  u16* wv_b  = wk_b  + 4194304;
  u16* wo_b  = wv_b  + 4194304;

  CvtArgs ca;
  ca.src[0]=hs; ca.src[1]=Wq; ca.src[2]=Wk; ca.src[3]=Wv; ca.src[4]=Wo;
  ca.dst[0]=hs_b; ca.dst[1]=wq_b; ca.dst[2]=wk_b; ca.dst[3]=wv_b; ca.dst[4]=wo_b;
  ca.nblk[0]=4096; ca.nblk[1]=2048; ca.nblk[2]=2048; ca.nblk[3]=2048; ca.nblk[4]=2048;

  dim3 blk(256);
  cvt_bf16<<<dim3(4096, 5), blk, 0, stream>>>(ca);

  dim3 g(32, 16);
  gemm_nt<0><<<g, blk, 0, stream>>>(hs_b, wq_b, q_ws,  cosp, sinp);
  gemm_nt<0><<<g, blk, 0, stream>>>(hs_b, wk_b, k_ws,  cosp, sinp);
  gemm_nt<1><<<g, blk, 0, stream>>>(hs_b, wv_b, vt_ws, nullptr, nullptr);
  attn_fwd<<<dim3(16, 16, 2), blk, 0, stream>>>(q_ws, k_ws, vt_ws, ao_ws);
  gemm_nt<2><<<g, blk, 0, stream>>>(ao_ws, wo_b, d_out, nullptr, nullptr);
}

// Round 6
// 399.029 us; speedup vs baseline: 1.2950x; 1.0902x over previous
//
#include <hip/hip_runtime.h>

typedef unsigned short u16;
typedef unsigned int   u32;
typedef __attribute__((ext_vector_type(8))) __bf16 bf16x8;
typedef __attribute__((ext_vector_type(8))) unsigned short u16x8;
typedef __attribute__((ext_vector_type(4))) float f32x4;

#define DEVINL static __device__ __forceinline__
#define MFMA16(a,b,c) __builtin_amdgcn_mfma_f32_16x16x32_bf16((a),(b),(c),0,0,0)

// Async global->LDS, 16B per lane. LDS dest must be (wave-uniform base + lane*16).
#define GLOAD16(g, l) __builtin_amdgcn_global_load_lds( \
    (const __attribute__((address_space(1))) void*)(g), \
    (__attribute__((address_space(3))) void*)(l), 16, 0, 0)

constexpr float ATT_SCALE = 0.08838834764831845f;  // 128^-0.5

DEVINL u16 f2bf(float f) {
  union { float f; u32 u; } v; v.f = f;
  u32 r = v.u + 0x7fffu + ((v.u >> 16) & 1u);   // RNE, finite inputs only
  return (u16)(r >> 16);
}

// ---------------------------------------------------------------------------
// One-shot fp32 -> bf16 conversion of hs + the 4 weight matrices.
// ---------------------------------------------------------------------------
struct CvtArgs {
  const float* src[5];
  u16*         dst[5];
  int          nblk[5];
};

__global__ __launch_bounds__(256) void cvt_bf16(CvtArgs a) {
  const int z = blockIdx.y;
  if (blockIdx.x >= a.nblk[z]) return;
  const size_t i = ((size_t)blockIdx.x * 256 + threadIdx.x) * 8;
  const float* s = a.src[z] + i;
  float4 x0 = *(const float4*)(s);
  float4 x1 = *(const float4*)(s + 4);
  u16x8 r;
  r[0]=f2bf(x0.x); r[1]=f2bf(x0.y); r[2]=f2bf(x0.z); r[3]=f2bf(x0.w);
  r[4]=f2bf(x1.x); r[5]=f2bf(x1.y); r[6]=f2bf(x1.z); r[7]=f2bf(x1.w);
  *(u16x8*)(a.dst[z] + i) = r;
}

// ---------------------------------------------------------------------------
// Phased NT-GEMM: C[M,N] = A[M,K] * W[N,K]^T, M=4096, K=2048, all-bf16 in.
// BM=256, BN=128, BK=64. 512 threads = 8 waves (2M x 4N); wave tile 128x32,
// cols = {wn*16..+16} U {64+wn*16..+16} so RoPE's (d, d+64) pair is in-lane.
// LDS: 3-slot ring (48KB/slot = A 256x64 + B 128x64), distance-2 prefetch:
// iter i computes tile i from slot i%3, stages tile i+2 into slot (i+2)%3
// (never concurrently read -> WAR-safe); vmcnt(6) once per K-tile drains
// tile i+1 exactly. 4 phases/K-tile, 8 MFMA each, T2 swizzle + T5 setprio.
// FUSED=1: QKV fused over N=6144 (z = bn>>4 picks matrix; epi RoPE / V^T).
// FUSED=0: plain fp32 store (out projection).
// ---------------------------------------------------------------------------
#define SLOT_U16 24576                // 48KB per ring slot
#define A_HALF_U16 8192               // 128x64
#define B_OFF_U16 16384               // B tile base within slot
#define B_HALF_U16 4096               // 64x64

#define STAGE_AH(s, half, ktile) do {                                          \
    _Pragma("unroll")                                                          \
    for (int it_ = 0; it_ < 2; ++it_) {                                        \
      const u32 p_  = it_*512 + t;                                             \
      const u32 gl_ = p_ ^ ((p_ >> 3) & 7u);                                   \
      GLOAD16(A + (size_t)(bm*256 + (half)*128 + (gl_ >> 3))*2048              \
                 + (ktile)*64 + (gl_ & 7u)*8,                                  \
              &lds[(s)*SLOT_U16 + (half)*A_HALF_U16 + p_*8]);                  \
    } } while (0)

#define STAGE_BH(s, half, ktile) do {                                          \
    const u32 p_  = (u32)t;                                                    \
    const u32 gl_ = p_ ^ ((p_ >> 3) & 7u);                                     \
    GLOAD16(Wg + (size_t)(bnl*128 + (half)*64 + (gl_ >> 3))*2048               \
               + (ktile)*64 + (gl_ & 7u)*8,                                    \
            &lds[(s)*SLOT_U16 + B_OFF_U16 + (half)*B_HALF_U16 + p_*8]);        \
  } while (0)

// A frag: rows wm*128 + mfg*16 + c; B frag: cols nf*64 + wn*16 + c.
#define LDA(s, mfg, ks) (*(const bf16x8*)&lds[(s)*SLOT_U16 + wm*A_HALF_U16 +   \
    ((((mfg)*16 + c)*64 + (ks)*32 + qq*8) ^ ((u32)(c & 7) << 3))])
#define LDB(s, nf, ks)  (*(const bf16x8*)&lds[(s)*SLOT_U16 + B_OFF_U16 +       \
    (nf)*B_HALF_U16 + (((wn*16 + c)*64 + (ks)*32 + qq*8) ^ ((u32)(c & 7) << 3))])

#define PHASE(s, mq, ks, LOADB, VMW, ...) do {                                 \
    if (LOADB) { bfr0 = LDB(s, 0, ks); bfr1 = LDB(s, 1, ks); }                 \
    bf16x8 a0_ = LDA(s, (mq)*4+0, ks);                                         \
    bf16x8 a1_ = LDA(s, (mq)*4+1, ks);                                         \
    bf16x8 a2_ = LDA(s, (mq)*4+2, ks);                                         \
    bf16x8 a3_ = LDA(s, (mq)*4+3, ks);                                         \
    __VA_ARGS__;                                                               \
    if (VMW) { asm volatile("s_waitcnt vmcnt(6)" ::: "memory"); }              \
    __builtin_amdgcn_s_barrier();                                              \
    asm volatile("s_waitcnt lgkmcnt(0)" ::: "memory");                         \
    __builtin_amdgcn_sched_barrier(0);                                         \
    __builtin_amdgcn_s_setprio(1);                                             \
    acc[(mq)*4+0][0] = MFMA16(a0_, bfr0, acc[(mq)*4+0][0]);                    \
    acc[(mq)*4+1][0] = MFMA16(a1_, bfr0, acc[(mq)*4+1][0]);                    \
    acc[(mq)*4+2][0] = MFMA16(a2_, bfr0, acc[(mq)*4+2][0]);                    \
    acc[(mq)*4+3][0] = MFMA16(a3_, bfr0, acc[(mq)*4+3][0]);                    \
    acc[(mq)*4+0][1] = MFMA16(a0_, bfr1, acc[(mq)*4+0][1]);                    \
    acc[(mq)*4+1][1] = MFMA16(a1_, bfr1, acc[(mq)*4+1][1]);                    \
    acc[(mq)*4+2][1] = MFMA16(a2_, bfr1, acc[(mq)*4+2][1]);                    \
    acc[(mq)*4+3][1] = MFMA16(a3_, bfr1, acc[(mq)*4+3][1]);                    \
    __builtin_amdgcn_s_setprio(0);                                             \
    __builtin_amdgcn_s_barrier();                                              \
  } while (0)

template<int FUSED>
__global__ __launch_bounds__(512, 1)
void gemm8(const u16* __restrict__ A, const u16* __restrict__ W0,
           const u16* __restrict__ W1, const u16* __restrict__ W2,
           u16* __restrict__ outq, u16* __restrict__ outk,
           u16* __restrict__ outv, float* __restrict__ outf,
           const float* __restrict__ cosp, const float* __restrict__ sinp)
{
  __shared__ __attribute__((aligned(16))) u16 lds[3*SLOT_U16];   // 144KB

  const int t = threadIdx.x;
  const int lane = t & 63, w = t >> 6;
  const int wm = w >> 2, wn = w & 3;
  const int c = lane & 15, qq = lane >> 4;
  const int bm = blockIdx.x, bn = blockIdx.y;
  const int z   = FUSED ? (bn >> 4) : 3;
  const int bnl = FUSED ? (bn & 15) : bn;
  const u16* Wg = FUSED ? (z == 0 ? W0 : (z == 1 ? W1 : W2)) : W0;

  f32x4 acc[8][2] = {};

  // Prologue: tiles 0,1 into slots 0,1; drain tile 0 (vmcnt: 12 issued - 6).
  STAGE_AH(0, 0, 0); STAGE_AH(0, 1, 0); STAGE_BH(0, 0, 0); STAGE_BH(0, 1, 0);
  STAGE_AH(1, 0, 1); STAGE_AH(1, 1, 1); STAGE_BH(1, 0, 1); STAGE_BH(1, 1, 1);
  asm volatile("s_waitcnt vmcnt(6)" ::: "memory");
  __builtin_amdgcn_s_barrier();

  bf16x8 bfr0, bfr1;
  int slot = 0;
  #pragma unroll 1
  for (int i = 0; i < 32; ++i) {
    const int s2 = (slot >= 1) ? slot - 1 : 2;     // (slot+2)%3
    const int tn = (i < 30) ? i + 2 : 31;          // clamped tail restage
    PHASE(slot, 0, 0, 1, 0, STAGE_AH(s2, 0, tn));
    PHASE(slot, 1, 0, 0, 0, STAGE_AH(s2, 1, tn));
    PHASE(slot, 0, 1, 1, 0, STAGE_BH(s2, 0, tn); STAGE_BH(s2, 1, tn));
    PHASE(slot, 1, 1, 0, 1, );
    slot = (slot == 2) ? 0 : slot + 1;
  }

  __syncthreads();   // full drain (junk tail prefetches) before LDS reuse

  if (!FUSED) {
    #pragma unroll
    for (int mfg = 0; mfg < 8; ++mfg)
      #pragma unroll
      for (int nf = 0; nf < 2; ++nf)
        #pragma unroll
        for (int r = 0; r < 4; ++r) {
          int row = bm*256 + wm*128 + mfg*16 + qq*4 + r;
          int col = bnl*128 + nf*64 + wn*16 + c;
          outf[(size_t)row*2048 + col] = acc[mfg][nf][r];
        }
    return;
  }

  if (z <= 1) {
    // RoPE epilogue: nf=0 holds d=wn*16+c (<64), nf=1 holds d+64.
    u16* qk = (z == 0) ? outq : outk;
    const int d1 = wn*16 + c, d2 = d1 + 64;
    #pragma unroll
    for (int mfg = 0; mfg < 8; ++mfg)
      #pragma unroll
      for (int r = 0; r < 4; ++r) {
        int m  = bm*256 + wm*128 + mfg*16 + qq*4 + r;
        int bb = m >> 11, s = m & 2047;
        const float* cs = cosp + s*128;
        const float* sn = sinp + s*128;
        u16* orow = qk + ((size_t)(bb*16 + bnl)*2048 + s)*128;
        float v1 = acc[mfg][0][r], v2 = acc[mfg][1][r];
        orow[d1] = f2bf(v1*cs[d1] - v2*sn[d1]);
        orow[d2] = f2bf(v2*cs[d2] + v1*sn[d2]);
      }
  } else {
    // V: transpose 256x128 block via LDS (stride 264 breaks bank alignment),
    // store [b,h,d,s] coalesced.
    #pragma unroll
    for (int mfg = 0; mfg < 8; ++mfg)
      #pragma unroll
      for (int nf = 0; nf < 2; ++nf)
        #pragma unroll
        for (int r = 0; r < 4; ++r)
          lds[(nf*64 + wn*16 + c)*264 + wm*128 + mfg*16 + qq*4 + r] =
              f2bf(acc[mfg][nf][r]);
    __syncthreads();
    const int d = t >> 2, seg = t & 3;
    const int bb = bm >> 3, s0 = (bm & 7) * 256;
    u16* og = outv + ((size_t)(bb*16 + bnl)*128 + d)*2048 + s0 + seg*64;
    #pragma unroll
    for (int j = 0; j < 8; ++j)
      *(u16x8*)&og[j*8] = *(const u16x8*)&lds[d*264 + seg*64 + j*8];
  }
}

// ---------------------------------------------------------------------------
// Flash attention, causal, PAIRED q-tiles (validated round 4: 104 us).
// ---------------------------------------------------------------------------
__global__ __launch_bounds__(256, 2)
void attn_fwd(const u16* __restrict__ qw, const u16* __restrict__ kw,
              const u16* __restrict__ vw, u16* __restrict__ ow)
{
  __shared__ __attribute__((aligned(16))) u16 Klds[2][64*128];
  __shared__ __attribute__((aligned(16))) u16 Vlds[2][128*64];
  __shared__ __attribute__((aligned(16))) u16 Plds[4][16*72];

  const int t = threadIdx.x, lane = t & 63, w = t >> 6;
  const int c = lane & 15, qq = lane >> 4;
  const int ip = blockIdx.x, h = blockIdx.y, b = blockIdx.z;
  const int qlo = ip, qhi = 31 - ip;

  const size_t bh = (size_t)b*16 + h;
  const u16* Qg = qw + bh*(2048*128);
  const u16* Kg = kw + bh*(2048*128);
  const u16* Vg = vw + bh*(128*2048);
  u16* pw = &Plds[w][0];

  bf16x8 qf_hi[4], qf_lo[4];
  {
    const u16* qh = Qg + (size_t)(qhi*64 + w*16 + c)*128;
    const u16* ql = Qg + (size_t)(qlo*64 + w*16 + c)*128;
    #pragma unroll
    for (int ds = 0; ds < 4; ++ds) {
      qf_hi[ds] = *(const bf16x8*)(qh + ds*32 + qq*8);
      qf_lo[ds] = *(const bf16x8*)(ql + ds*32 + qq*8);
    }
  }

  float m_hi[4] = {-1e30f,-1e30f,-1e30f,-1e30f};
  float l_hi[4] = {0.f,0.f,0.f,0.f};
  f32x4 o_hi[8] = {};
  float m_lo[4] = {-1e30f,-1e30f,-1e30f,-1e30f};
  float l_lo[4] = {0.f,0.f,0.f,0.f};
  f32x4 o_lo[8] = {};

#define ASTAGE(BUF, KT) do {                                                  \
    const u16* kbase = Kg + (size_t)(KT)*8192;                                \
    _Pragma("unroll")                                                         \
    for (int it = 0; it < 4; ++it) {                                          \
      const u32 p  = it*256 + t;                                              \
      const u32 gl = p ^ ((p >> 4) & 7u);                                     \
      GLOAD16(kbase + gl*8, &Klds[BUF][p*8]);                                 \
    }                                                                         \
    _Pragma("unroll")                                                         \
    for (int it = 0; it < 4; ++it) {                                          \
      const u32 p  = it*256 + t;                                              \
      const u32 gl = p ^ ((p >> 3) & 7u);                                     \
      GLOAD16(Vg + (size_t)(gl >> 3)*2048 + (KT)*64 + (gl & 7u)*8,            \
              &Vlds[BUF][p*8]);                                               \
    }                                                                         \
  } while (0)

#define APROCESS(QF, OACC, MR, LR, QBASE, DIAG, BUF) do {                     \
    f32x4 sc[4] = {};                                                         \
    __builtin_amdgcn_s_setprio(1);                                            \
    _Pragma("unroll")                                                         \
    for (int ds = 0; ds < 4; ++ds) {                                          \
      _Pragma("unroll")                                                       \
      for (int nj = 0; nj < 4; ++nj) {                                        \
        const u32 row = nj*16 + c;                                            \
        const u32 p = (row*128 + ds*32 + qq*8) ^ ((row & 7u) << 3);           \
        bf16x8 kb = *(const bf16x8*)&Klds[BUF][p];                            \
        sc[nj] = MFMA16(QF[ds], kb, sc[nj]);                                  \
      }                                                                       \
    }                                                                         \
    __builtin_amdgcn_s_setprio(0);                                            \
    const int qg0 = (QBASE) + w*16 + qq*4;                                    \
    float escale[4];                                                          \
    _Pragma("unroll")                                                         \
    for (int r = 0; r < 4; ++r) {                                             \
      float mx = -1e30f;                                                      \
      _Pragma("unroll")                                                       \
      for (int nj = 0; nj < 4; ++nj) {                                        \
        float s = sc[nj][r] * ATT_SCALE;                                      \
        if ((DIAG) && (kt*64 + nj*16 + c) > (qg0 + r)) s = -1e30f;            \
        sc[nj][r] = s;                                                        \
        mx = fmaxf(mx, s);                                                    \
      }                                                                       \
      mx = fmaxf(mx, __shfl_xor(mx, 1));                                      \
      mx = fmaxf(mx, __shfl_xor(mx, 2));                                      \
      mx = fmaxf(mx, __shfl_xor(mx, 4));                                      \
      mx = fmaxf(mx, __shfl_xor(mx, 8));                                      \
      float mnew = fmaxf(MR[r], mx);                                          \
      escale[r] = __expf(MR[r] - mnew);                                       \
      MR[r] = mnew;                                                           \
      float sum = 0.f;                                                        \
      _Pragma("unroll")                                                       \
      for (int nj = 0; nj < 4; ++nj) {                                        \
        float pv = __expf(sc[nj][r] - mnew);                                  \
        sum += pv;                                                            \
        pw[(qq*4 + r)*72 + nj*16 + c] = f2bf(pv);                             \
      }                                                                       \
      sum += __shfl_xor(sum, 1);                                              \
      sum += __shfl_xor(sum, 2);                                              \
      sum += __shfl_xor(sum, 4);                                              \
      sum += __shfl_xor(sum, 8);                                              \
      LR[r] = LR[r]*escale[r] + sum;                                          \
    }                                                                         \
    _Pragma("unroll")                                                         \
    for (int nj8 = 0; nj8 < 8; ++nj8)                                         \
      _Pragma("unroll")                                                       \
      for (int r = 0; r < 4; ++r)                                             \
        OACC[nj8][r] *= escale[r];                                            \
    __builtin_amdgcn_s_setprio(1);                                            \
    _Pragma("unroll")                                                         \
    for (int ks = 0; ks < 2; ++ks) {                                          \
      bf16x8 pa = *(const bf16x8*)&pw[c*72 + ks*32 + qq*8];                   \
      _Pragma("unroll")                                                       \
      for (int nj8 = 0; nj8 < 8; ++nj8) {                                     \
        const u32 row = nj8*16 + c;                                           \
        const u32 p = (row*64 + ks*32 + qq*8) ^ ((row & 7u) << 3);            \
        bf16x8 vb = *(const bf16x8*)&Vlds[BUF][p];                            \
        OACC[nj8] = MFMA16(pa, vb, OACC[nj8]);                                \
      }                                                                       \
    }                                                                         \
    __builtin_amdgcn_s_setprio(0);                                            \
  } while (0)

  ASTAGE(0, 0);
  for (int kt = 0; kt <= qhi; ++kt) {
    const int cur = kt & 1;
    __syncthreads();
    if (kt < qhi) ASTAGE(cur ^ 1, kt + 1);
    APROCESS(qf_hi, o_hi, m_hi, l_hi, qhi*64, (kt == qhi), cur);
    if (kt <= qlo)
      APROCESS(qf_lo, o_lo, m_lo, l_lo, qlo*64, (kt == qlo), cur);
  }

#undef ASTAGE
#undef APROCESS

  {
    float inv[4];
    #pragma unroll
    for (int r = 0; r < 4; ++r) inv[r] = 1.0f / l_hi[r];
    u16* og = ow + ((size_t)b*2048 + qhi*64 + w*16)*2048 + h*128;
    #pragma unroll
    for (int nj8 = 0; nj8 < 8; ++nj8)
      #pragma unroll
      for (int r = 0; r < 4; ++r)
        og[(size_t)(qq*4 + r)*2048 + nj8*16 + c] = f2bf(o_hi[nj8][r]*inv[r]);
  }
  {
    float inv[4];
    #pragma unroll
    for (int r = 0; r < 4; ++r) inv[r] = 1.0f / l_lo[r];
    u16* og = ow + ((size_t)b*2048 + qlo*64 + w*16)*2048 + h*128;
    #pragma unroll
    for (int nj8 = 0; nj8 < 8; ++nj8)
      #pragma unroll
      for (int r = 0; r < 4; ++r)
        og[(size_t)(qq*4 + r)*2048 + nj8*16 + c] = f2bf(o_lo[nj8][r]*inv[r]);
  }
}

extern "C" void kernel_launch(void* const* d_in, const int* in_sizes, int n_in,
                              void* d_out, int out_size, void* d_ws, size_t ws_size,
                              hipStream_t stream)
{
  const float* hs   = (const float*)d_in[0];
  const float* cosp = (const float*)d_in[1];
  const float* sinp = (const float*)d_in[2];
  const float* Wq   = (const float*)d_in[3];
  const float* Wk   = (const float*)d_in[4];
  const float* Wv   = (const float*)d_in[5];
  const float* Wo   = (const float*)d_in[6];

  u16* q_ws  = (u16*)d_ws;
  u16* k_ws  = q_ws  + 8388608;
  u16* vt_ws = k_ws  + 8388608;
  u16* ao_ws = vt_ws + 8388608;
  u16* hs_b  = ao_ws + 8388608;
  u16* wq_b  = hs_b  + 8388608;
  u16* wk_b  = wq_b  + 4194304;
  u16* wv_b  = wk_b  + 4194304;
  u16* wo_b  = wv_b  + 4194304;

  CvtArgs ca;
  ca.src[0]=hs; ca.src[1]=Wq; ca.src[2]=Wk; ca.src[3]=Wv; ca.src[4]=Wo;
  ca.dst[0]=hs_b; ca.dst[1]=wq_b; ca.dst[2]=wk_b; ca.dst[3]=wv_b; ca.dst[4]=wo_b;
  ca.nblk[0]=4096; ca.nblk[1]=2048; ca.nblk[2]=2048; ca.nblk[3]=2048; ca.nblk[4]=2048;

  cvt_bf16<<<dim3(4096, 5), dim3(256), 0, stream>>>(ca);

  gemm8<1><<<dim3(16, 48), dim3(512), 0, stream>>>(
      hs_b, wq_b, wk_b, wv_b, q_ws, k_ws, vt_ws, nullptr, cosp, sinp);

  attn_fwd<<<dim3(16, 16, 2), dim3(256), 0, stream>>>(q_ws, k_ws, vt_ws, ao_ws);

  gemm8<0><<<dim3(16, 16), dim3(512), 0, stream>>>(
      ao_ws, wo_b, nullptr, nullptr, nullptr, nullptr, nullptr,
      (float*)d_out, nullptr, nullptr);
}